// Round 1
// baseline (2566.623 us; speedup 1.0000x reference)
//
#include <hip/hip_runtime.h>

// RGCNConv basis-decomposed:
//   out = [seg_sum(x[src] by (dst,rel)) | x] @ [W_r stacked ; root] + bias
// Phases: zero s -> build WcatT (bf16, transposed, padded) -> atomic scatter -> bf16 MFMA GEMM

#define N_NODES 20000
#define N_EDGES 640000
#define IN_DIM  256
#define OUT_DIM 800
#define NREL    8
#define KS      2048            // NREL * IN_DIM
#define KTOT    2304            // KS + IN_DIM
#define NPAD    896             // 7 * 128 (padded N for GEMM B)

typedef float f32x4_t __attribute__((ext_vector_type(4)));
typedef short short8_t __attribute__((ext_vector_type(8)));

__device__ __forceinline__ unsigned short f2bf(float f) {
  // round-to-nearest-even f32 -> bf16 (inputs finite)
  unsigned u = __float_as_uint(f);
  u += 0x7fffu + ((u >> 16) & 1u);
  return (unsigned short)(u >> 16);
}

__global__ void zero_s_kernel(float4* __restrict__ p) {
  p[(size_t)blockIdx.x * blockDim.x + threadIdx.x] = make_float4(0.f, 0.f, 0.f, 0.f);
}

// WcatT[n][k], n in [0,896), k in [0,2304). k<2048: W[r=k>>8][i=k&255][n]; else root[k-2048][n].
// n >= 800 zero-padded so GEMM B staging needs no guard.
__global__ void build_wcat_kernel(const float* __restrict__ bases,
                                  const float* __restrict__ att,
                                  const float* __restrict__ root,
                                  unsigned short* __restrict__ wcatT) {
  const int k = blockIdx.x;                      // 0..2303
  const int n = blockIdx.y * 128 + threadIdx.x;  // 0..895
  float v = 0.f;
  if (n < OUT_DIM) {
    if (k < KS) {
      const int r = k >> 8, i = k & 255;
      #pragma unroll
      for (int b = 0; b < 8; ++b)
        v += att[r * 8 + b] * bases[((size_t)b * IN_DIM + i) * OUT_DIM + n];
    } else {
      v = root[(size_t)(k - KS) * OUT_DIM + n];
    }
  }
  wcatT[(size_t)n * KTOT + k] = f2bf(v);
}

// 4 edges per 256-thread block; 64 lanes/edge; float4 per lane -> 4 f32 atomics.
__global__ void scatter_kernel(const float* __restrict__ x,
                               const int* __restrict__ ei,
                               const int* __restrict__ et,
                               float* __restrict__ s) {
  const int e = __builtin_amdgcn_readfirstlane(blockIdx.x * 4 + (threadIdx.x >> 6));
  const int lane = threadIdx.x & 63;
  const int src = ei[e];
  const int dst = ei[N_EDGES + e];
  const int r   = et[e];
  const float4 v = ((const float4*)x)[(size_t)src * 64 + lane];
  float* p = s + (((size_t)(dst * NREL + r)) << 8) + lane * 4;
  unsafeAtomicAdd(p + 0, v.x);
  unsafeAtomicAdd(p + 1, v.y);
  unsafeAtomicAdd(p + 2, v.z);
  unsafeAtomicAdd(p + 3, v.w);
}

// C[M=20000][800] = A[M][2304] @ B[2304][800] + bias.  A: k<2048 from s (f32),
// k>=2048 from x (f32), cast to bf16 during staging.  B: WcatT bf16 (pre-transposed).
// 128x128 tile, BK=64, 4 waves (2x2) of 64x64, mfma_f32_16x16x32_bf16.
__global__ __launch_bounds__(256) void gemm_kernel(
    const float* __restrict__ s, const float* __restrict__ x,
    const unsigned short* __restrict__ wcatT,
    const float* __restrict__ bias, float* __restrict__ out) {
  __shared__ __align__(16) unsigned short As[128 * 64];
  __shared__ __align__(16) unsigned short Bs[128 * 64];

  const int tid  = threadIdx.x;
  const int col0 = blockIdx.x * 128;   // N tile (0..6)
  const int row0 = blockIdx.y * 128;   // M tile (0..156)

  // staging role: thread t -> row t>>1 (0..127), 32-elem k-chunk (t&1)
  const int srow  = tid >> 1;
  const int shalf = tid & 1;

  const int wid = tid >> 6, lane = tid & 63;
  const int wr = wid >> 1, wc = wid & 1;
  const int la = lane & 15, lg = lane >> 4;

  f32x4_t acc[4][4];
  #pragma unroll
  for (int i = 0; i < 4; ++i)
    #pragma unroll
    for (int j = 0; j < 4; ++j)
      acc[i][j] = (f32x4_t)(0.0f);

  const int gm  = row0 + srow;
  // clamp OOB rows (block 156): their C rows are never stored, value irrelevant
  const int gmc = (gm < N_NODES) ? gm : 0;
  const int gn  = col0 + srow;   // < 896 always (WcatT padded)

  for (int kt = 0; kt < KTOT / 64; ++kt) {
    const int kbase = kt * 64 + shalf * 32;
    // ---- issue global loads (A: f32 source; B: bf16 copy) ----
    const float* srcA = (kbase < KS)
        ? (s + (size_t)gmc * KS + kbase)
        : (x + (size_t)gmc * IN_DIM + (kbase - KS));
    const float4* pa = (const float4*)srcA;
    float4 va[8];
    #pragma unroll
    for (int q = 0; q < 8; ++q) va[q] = pa[q];

    const uint4* pb = (const uint4*)(wcatT + (size_t)gn * KTOT + kbase);
    uint4 vb[4];
    #pragma unroll
    for (int q = 0; q < 4; ++q) vb[q] = pb[q];

    __syncthreads();   // previous tile's compute done before overwrite
    #pragma unroll
    for (int q = 0; q < 4; ++q) {
      union { unsigned short u[8]; uint4 q4; } pk;
      const float4 f0 = va[q * 2], f1 = va[q * 2 + 1];
      pk.u[0] = f2bf(f0.x); pk.u[1] = f2bf(f0.y);
      pk.u[2] = f2bf(f0.z); pk.u[3] = f2bf(f0.w);
      pk.u[4] = f2bf(f1.x); pk.u[5] = f2bf(f1.y);
      pk.u[6] = f2bf(f1.z); pk.u[7] = f2bf(f1.w);
      const int off = (srow * 128 + shalf * 64 + q * 16) ^ ((srow & 7) << 4);
      *(uint4*)((char*)As + off) = pk.q4;
      *(uint4*)((char*)Bs + off) = vb[q];
    }
    __syncthreads();

    // ---- compute: 2 k-steps of 16 MFMAs ----
    #pragma unroll
    for (int ks = 0; ks < 2; ++ks) {
      short8_t af[4], bfr[4];
      #pragma unroll
      for (int mf = 0; mf < 4; ++mf) {
        const int r = wr * 64 + mf * 16 + la;
        const int off = (r * 128 + (ks * 32 + lg * 8) * 2) ^ ((r & 7) << 4);
        union { uint4 q4; short8_t h; } u;
        u.q4 = *(const uint4*)((const char*)As + off);
        af[mf] = u.h;
      }
      #pragma unroll
      for (int nf = 0; nf < 4; ++nf) {
        const int r = wc * 64 + nf * 16 + la;
        const int off = (r * 128 + (ks * 32 + lg * 8) * 2) ^ ((r & 7) << 4);
        union { uint4 q4; short8_t h; } u;
        u.q4 = *(const uint4*)((const char*)Bs + off);
        bfr[nf] = u.h;
      }
      #pragma unroll
      for (int mf = 0; mf < 4; ++mf)
        #pragma unroll
        for (int nf = 0; nf < 4; ++nf)
          acc[mf][nf] = __builtin_amdgcn_mfma_f32_16x16x32_bf16(
              af[mf], bfr[nf], acc[mf][nf], 0, 0, 0);
    }
  }

  // ---- epilogue: C = acc + bias, guarded ----
  #pragma unroll
  for (int mf = 0; mf < 4; ++mf) {
    #pragma unroll
    for (int nf = 0; nf < 4; ++nf) {
      const int gcol = col0 + wc * 64 + nf * 16 + la;
      if (gcol < OUT_DIM) {
        const float bv = bias[gcol];
        const int gr0 = row0 + wr * 64 + mf * 16 + lg * 4;
        #pragma unroll
        for (int j = 0; j < 4; ++j) {
          const int gr = gr0 + j;
          if (gr < N_NODES)
            out[(size_t)gr * OUT_DIM + gcol] = acc[mf][nf][j] + bv;
        }
      }
    }
  }
}

extern "C" void kernel_launch(void* const* d_in, const int* in_sizes, int n_in,
                              void* d_out, int out_size, void* d_ws, size_t ws_size,
                              hipStream_t stream) {
  const float* x     = (const float*)d_in[0];
  const int*   ei    = (const int*)d_in[1];
  const int*   et    = (const int*)d_in[2];
  const float* bases = (const float*)d_in[3];
  const float* att   = (const float*)d_in[4];
  const float* root  = (const float*)d_in[5];
  const float* bias  = (const float*)d_in[6];
  float* out = (float*)d_out;

  // workspace layout: s f32 [20000*8*256] (163,840,000 B) | WcatT bf16 [896*2304] (4,128,768 B)
  float* s = (float*)d_ws;
  unsigned short* wcatT =
      (unsigned short*)((char*)d_ws + (size_t)N_NODES * NREL * IN_DIM * 4);

  // zero s: 40.96M floats = 10.24M float4 = 40000 blocks x 256
  zero_s_kernel<<<40000, 256, 0, stream>>>((float4*)s);
  build_wcat_kernel<<<dim3(KTOT, 7), 128, 0, stream>>>(bases, att, root, wcatT);
  scatter_kernel<<<N_EDGES / 4, 256, 0, stream>>>(x, ei, et, s);
  gemm_kernel<<<dim3(7, 157), 256, 0, stream>>>(s, x, wcatT, bias, out);
}

// Round 2
// 628.623 us; speedup vs baseline: 4.0829x; 4.0829x over previous
//
#include <hip/hip_runtime.h>

// RGCNConv basis-decomposed, sort-based (atomic-free) aggregation:
//   Abf = [seg_sum(x[src] by (dst,rel)) | x]  (bf16, [N][2304])
//   out = Abf @ [W_r stacked ; root] + bias   (bf16 MFMA, f32 out)
// Pipeline: zero cnt -> histogram -> scan(3) -> reorder -> aggregate(+cast)
//           -> xcast -> wcat -> GEMM

#define N_NODES 20000
#define N_EDGES 640000
#define IN_DIM  256
#define OUT_DIM 800
#define NREL    8
#define NSEG    160000          // N_NODES * NREL
#define KS      2048            // NREL * IN_DIM
#define KTOT    2304            // KS + IN_DIM
#define NPAD    896             // 7 * 128 (padded N for GEMM B)
#define NB      625             // NSEG / 256 scan blocks

typedef float f32x4_t __attribute__((ext_vector_type(4)));
typedef short short8_t __attribute__((ext_vector_type(8)));

__device__ __forceinline__ unsigned short f2bf(float f) {
  unsigned u = __float_as_uint(f);
  u += 0x7fffu + ((u >> 16) & 1u);
  return (unsigned short)(u >> 16);
}

// ---------------- sort pipeline ----------------

__global__ void zero_counts_kernel(int* __restrict__ cnt) {
  cnt[blockIdx.x * 256 + threadIdx.x] = 0;
}

__global__ void hist_kernel(const int* __restrict__ ei, const int* __restrict__ et,
                            int* __restrict__ cnt) {
  const int e = blockIdx.x * 256 + threadIdx.x;
  const int seg = ei[N_EDGES + e] * NREL + et[e];
  atomicAdd(&cnt[seg], 1);
}

__global__ void scan_reduce_kernel(const int* __restrict__ cnt, int* __restrict__ bsum) {
  __shared__ int sm[256];
  const int t = threadIdx.x;
  sm[t] = cnt[blockIdx.x * 256 + t];
  __syncthreads();
  for (int s = 128; s > 0; s >>= 1) {
    if (t < s) sm[t] += sm[t + s];
    __syncthreads();
  }
  if (t == 0) bsum[blockIdx.x] = sm[0];
}

__global__ void scan_bsum_kernel(int* __restrict__ bsum) {
  __shared__ int sm[1024];
  const int t = threadIdx.x;
  const int v = (t < NB) ? bsum[t] : 0;
  sm[t] = v;
  __syncthreads();
  for (int s = 1; s < 1024; s <<= 1) {
    const int a = (t >= s) ? sm[t - s] : 0;
    __syncthreads();
    sm[t] += a;
    __syncthreads();
  }
  if (t < NB) bsum[t] = sm[t] - v;   // exclusive
}

__global__ void scan_final_kernel(const int* __restrict__ cnt, const int* __restrict__ bsum,
                                  int* __restrict__ off, int* __restrict__ cur) {
  __shared__ int sm[256];
  const int t = threadIdx.x;
  const int g = blockIdx.x * 256 + t;
  const int v = cnt[g];
  sm[t] = v;
  __syncthreads();
  for (int s = 1; s < 256; s <<= 1) {
    const int a = (t >= s) ? sm[t - s] : 0;
    __syncthreads();
    sm[t] += a;
    __syncthreads();
  }
  const int ex = sm[t] - v + bsum[blockIdx.x];
  off[g] = ex;
  cur[g] = ex;
}

__global__ void reorder_kernel(const int* __restrict__ ei, const int* __restrict__ et,
                               int* __restrict__ cur, int* __restrict__ sorted_src) {
  const int e = blockIdx.x * 256 + threadIdx.x;
  const int seg = ei[N_EDGES + e] * NREL + et[e];
  const int pos = atomicAdd(&cur[seg], 1);
  sorted_src[pos] = ei[e];
}

// One wave per segment: gather x rows, f32-accumulate, write bf16 into Abf s-part.
__global__ void aggregate_kernel(const float* __restrict__ x,
                                 const int* __restrict__ cnt, const int* __restrict__ off,
                                 const int* __restrict__ sorted_src,
                                 unsigned short* __restrict__ abf) {
  const int seg = __builtin_amdgcn_readfirstlane(blockIdx.x * 4 + (threadIdx.x >> 6));
  const int lane = threadIdx.x & 63;
  const int ne = cnt[seg];
  const int o  = off[seg];
  const float4* x4 = (const float4*)x;
  float4 acc = make_float4(0.f, 0.f, 0.f, 0.f);
  float4 acc2 = make_float4(0.f, 0.f, 0.f, 0.f);
  int j = 0;
  for (; j + 1 < ne; j += 2) {
    const int s0 = sorted_src[o + j];
    const int s1 = sorted_src[o + j + 1];
    const float4 a = x4[(size_t)s0 * 64 + lane];
    const float4 b = x4[(size_t)s1 * 64 + lane];
    acc.x += a.x; acc.y += a.y; acc.z += a.z; acc.w += a.w;
    acc2.x += b.x; acc2.y += b.y; acc2.z += b.z; acc2.w += b.w;
  }
  if (j < ne) {
    const float4 a = x4[(size_t)sorted_src[o + j] * 64 + lane];
    acc.x += a.x; acc.y += a.y; acc.z += a.z; acc.w += a.w;
  }
  acc.x += acc2.x; acc.y += acc2.y; acc.z += acc2.z; acc.w += acc2.w;
  const int node = seg >> 3, r = seg & 7;
  union { unsigned short u[4]; uint2 q; } pk;
  pk.u[0] = f2bf(acc.x); pk.u[1] = f2bf(acc.y);
  pk.u[2] = f2bf(acc.z); pk.u[3] = f2bf(acc.w);
  *(uint2*)(abf + (size_t)node * KTOT + r * IN_DIM + lane * 4) = pk.q;
}

// Fill Abf[:, 2048:2304] = bf16(x)
__global__ void xcast_kernel(const float* __restrict__ x, unsigned short* __restrict__ abf) {
  const int id = blockIdx.x * 256 + threadIdx.x;   // 20000*64
  const int row = id >> 6, lane = id & 63;
  const float4 v = ((const float4*)x)[(size_t)row * 64 + lane];
  union { unsigned short u[4]; uint2 q; } pk;
  pk.u[0] = f2bf(v.x); pk.u[1] = f2bf(v.y);
  pk.u[2] = f2bf(v.z); pk.u[3] = f2bf(v.w);
  *(uint2*)(abf + (size_t)row * KTOT + KS + lane * 4) = pk.q;
}

// WcatT[n][k], n in [0,896), k in [0,2304). n >= 800 zero-padded.
__global__ void build_wcat_kernel(const float* __restrict__ bases,
                                  const float* __restrict__ att,
                                  const float* __restrict__ root,
                                  unsigned short* __restrict__ wcatT) {
  const int k = blockIdx.x;
  const int n = blockIdx.y * 128 + threadIdx.x;
  float v = 0.f;
  if (n < OUT_DIM) {
    if (k < KS) {
      const int r = k >> 8, i = k & 255;
      #pragma unroll
      for (int b = 0; b < 8; ++b)
        v += att[r * 8 + b] * bases[((size_t)b * IN_DIM + i) * OUT_DIM + n];
    } else {
      v = root[(size_t)(k - KS) * OUT_DIM + n];
    }
  }
  wcatT[(size_t)n * KTOT + k] = f2bf(v);
}

// C[20000][800] = Abf[20000][2304] @ WcatT^T + bias.  128x128 tile, BK=64,
// 4 waves (2x2) of 64x64, mfma_f32_16x16x32_bf16, XOR-swizzled LDS.
__global__ __launch_bounds__(256) void gemm_kernel(
    const unsigned short* __restrict__ abf,
    const unsigned short* __restrict__ wcatT,
    const float* __restrict__ bias, float* __restrict__ out) {
  __shared__ __align__(16) unsigned short As[128 * 64];
  __shared__ __align__(16) unsigned short Bs[128 * 64];

  const int tid  = threadIdx.x;
  const int col0 = blockIdx.x * 128;
  const int row0 = blockIdx.y * 128;

  const int srow  = tid >> 1;    // 0..127
  const int shalf = tid & 1;     // 32-elem k-chunk

  const int wid = tid >> 6, lane = tid & 63;
  const int wr = wid >> 1, wc = wid & 1;
  const int la = lane & 15, lg = lane >> 4;

  f32x4_t acc[4][4];
  #pragma unroll
  for (int i = 0; i < 4; ++i)
    #pragma unroll
    for (int j = 0; j < 4; ++j)
      acc[i][j] = (f32x4_t)(0.0f);

  const int gm  = row0 + srow;
  const int gmc = (gm < N_NODES) ? gm : 0;   // OOB rows computed, never stored
  const int gn  = col0 + srow;               // < 896 (WcatT padded)

  for (int kt = 0; kt < KTOT / 64; ++kt) {
    const int kbase = kt * 64 + shalf * 32;
    const uint4* pa = (const uint4*)(abf + (size_t)gmc * KTOT + kbase);
    uint4 va[4];
    #pragma unroll
    for (int q = 0; q < 4; ++q) va[q] = pa[q];
    const uint4* pb = (const uint4*)(wcatT + (size_t)gn * KTOT + kbase);
    uint4 vb[4];
    #pragma unroll
    for (int q = 0; q < 4; ++q) vb[q] = pb[q];

    __syncthreads();
    #pragma unroll
    for (int q = 0; q < 4; ++q) {
      const int off = (srow * 128 + shalf * 64 + q * 16) ^ ((srow & 7) << 4);
      *(uint4*)((char*)As + off) = va[q];
      *(uint4*)((char*)Bs + off) = vb[q];
    }
    __syncthreads();

    #pragma unroll
    for (int ks = 0; ks < 2; ++ks) {
      short8_t af[4], bfr[4];
      #pragma unroll
      for (int mf = 0; mf < 4; ++mf) {
        const int r = wr * 64 + mf * 16 + la;
        const int off = (r * 128 + (ks * 32 + lg * 8) * 2) ^ ((r & 7) << 4);
        union { uint4 q4; short8_t h; } u;
        u.q4 = *(const uint4*)((const char*)As + off);
        af[mf] = u.h;
      }
      #pragma unroll
      for (int nf = 0; nf < 4; ++nf) {
        const int r = wc * 64 + nf * 16 + la;
        const int off = (r * 128 + (ks * 32 + lg * 8) * 2) ^ ((r & 7) << 4);
        union { uint4 q4; short8_t h; } u;
        u.q4 = *(const uint4*)((const char*)Bs + off);
        bfr[nf] = u.h;
      }
      #pragma unroll
      for (int mf = 0; mf < 4; ++mf)
        #pragma unroll
        for (int nf = 0; nf < 4; ++nf)
          acc[mf][nf] = __builtin_amdgcn_mfma_f32_16x16x32_bf16(
              af[mf], bfr[nf], acc[mf][nf], 0, 0, 0);
    }
  }

  #pragma unroll
  for (int mf = 0; mf < 4; ++mf) {
    #pragma unroll
    for (int nf = 0; nf < 4; ++nf) {
      const int gcol = col0 + wc * 64 + nf * 16 + la;
      if (gcol < OUT_DIM) {
        const float bv = bias[gcol];
        const int gr0 = row0 + wr * 64 + mf * 16 + lg * 4;
        #pragma unroll
        for (int j = 0; j < 4; ++j) {
          const int gr = gr0 + j;
          if (gr < N_NODES)
            out[(size_t)gr * OUT_DIM + gcol] = acc[mf][nf][j] + bv;
        }
      }
    }
  }
}

extern "C" void kernel_launch(void* const* d_in, const int* in_sizes, int n_in,
                              void* d_out, int out_size, void* d_ws, size_t ws_size,
                              hipStream_t stream) {
  const float* x     = (const float*)d_in[0];
  const int*   ei    = (const int*)d_in[1];
  const int*   et    = (const int*)d_in[2];
  const float* bases = (const float*)d_in[3];
  const float* att   = (const float*)d_in[4];
  const float* root  = (const float*)d_in[5];
  const float* bias  = (const float*)d_in[6];
  float* out = (float*)d_out;

  // workspace layout (16B-aligned chunks):
  char* p = (char*)d_ws;
  unsigned short* abf   = (unsigned short*)p;               p += (size_t)N_NODES * KTOT * 2;   // 92,160,000
  unsigned short* wcatT = (unsigned short*)p;               p += (size_t)NPAD * KTOT * 2;      //  4,128,768
  int* cnt        = (int*)p;                                p += (size_t)NSEG * 4;
  int* off        = (int*)p;                                p += (size_t)NSEG * 4;
  int* cur        = (int*)p;                                p += (size_t)NSEG * 4;
  int* sorted_src = (int*)p;                                p += (size_t)N_EDGES * 4;
  int* bsum       = (int*)p;                                p += 4096;

  zero_counts_kernel<<<NB, 256, 0, stream>>>(cnt);
  hist_kernel<<<N_EDGES / 256, 256, 0, stream>>>(ei, et, cnt);
  scan_reduce_kernel<<<NB, 256, 0, stream>>>(cnt, bsum);
  scan_bsum_kernel<<<1, 1024, 0, stream>>>(bsum);
  scan_final_kernel<<<NB, 256, 0, stream>>>(cnt, bsum, off, cur);
  reorder_kernel<<<N_EDGES / 256, 256, 0, stream>>>(ei, et, cur, sorted_src);
  aggregate_kernel<<<NSEG / 4, 256, 0, stream>>>(x, cnt, off, sorted_src, abf);
  xcast_kernel<<<N_NODES * 64 / 256, 256, 0, stream>>>(x, abf);
  build_wcat_kernel<<<dim3(KTOT, 7), 128, 0, stream>>>(bases, att, root, wcatT);
  gemm_kernel<<<dim3(7, 157), 256, 0, stream>>>(abf, wcatT, bias, out);
}

// Round 3
// 321.555 us; speedup vs baseline: 7.9819x; 1.9549x over previous
//
#include <hip/hip_runtime.h>

// RGCNConv basis-decomposed, sort-based aggregation + pipelined bf16 MFMA GEMM.
//   Abf = [seg_sum(x[src] by (dst,rel)) | x]  (bf16, [N][2304])
//   out = Abf @ WcatT^T + bias                (f32 out)

#define N_NODES 20000
#define N_EDGES 640000
#define IN_DIM  256
#define OUT_DIM 800
#define NREL    8
#define NSEG    160000          // N_NODES * NREL
#define KS      2048            // NREL * IN_DIM
#define KTOT    2304            // KS + IN_DIM
#define NPAD    1024            // padded N for GEMM B (4 x 256)
#define NB      625             // NSEG / 256 scan blocks

// GEMM geometry
#define BM 128
#define BN 256
#define BK 64
#define NKT (KTOT / BK)         // 36
#define MT  157                 // ceil(20000/128)
#define NT  4                   // 1024/256
#define NWG (MT * NT)           // 628

typedef float f32x4_t __attribute__((ext_vector_type(4)));
typedef short short8_t __attribute__((ext_vector_type(8)));

__device__ __forceinline__ unsigned short f2bf(float f) {
  unsigned u = __float_as_uint(f);
  u += 0x7fffu + ((u >> 16) & 1u);
  return (unsigned short)(u >> 16);
}

__device__ __forceinline__ void gload16(const void* g, void* l) {
  __builtin_amdgcn_global_load_lds(
      (const __attribute__((address_space(1))) void*)g,
      (__attribute__((address_space(3))) void*)l, 16, 0, 0);
}

// ---------------- sort pipeline ----------------

__global__ void zero_counts_kernel(int* __restrict__ cnt) {
  cnt[blockIdx.x * 256 + threadIdx.x] = 0;
}

__global__ void hist_kernel(const int* __restrict__ ei, const int* __restrict__ et,
                            int* __restrict__ cnt) {
  const int e = blockIdx.x * 256 + threadIdx.x;
  const int seg = ei[N_EDGES + e] * NREL + et[e];
  atomicAdd(&cnt[seg], 1);
}

__global__ void scan_reduce_kernel(const int* __restrict__ cnt, int* __restrict__ bsum) {
  __shared__ int sm[256];
  const int t = threadIdx.x;
  sm[t] = cnt[blockIdx.x * 256 + t];
  __syncthreads();
  for (int s = 128; s > 0; s >>= 1) {
    if (t < s) sm[t] += sm[t + s];
    __syncthreads();
  }
  if (t == 0) bsum[blockIdx.x] = sm[0];
}

__global__ void scan_bsum_kernel(int* __restrict__ bsum) {
  __shared__ int sm[1024];
  const int t = threadIdx.x;
  const int v = (t < NB) ? bsum[t] : 0;
  sm[t] = v;
  __syncthreads();
  for (int s = 1; s < 1024; s <<= 1) {
    const int a = (t >= s) ? sm[t - s] : 0;
    __syncthreads();
    sm[t] += a;
    __syncthreads();
  }
  if (t < NB) bsum[t] = sm[t] - v;   // exclusive
}

__global__ void scan_final_kernel(const int* __restrict__ cnt, const int* __restrict__ bsum,
                                  int* __restrict__ off, int* __restrict__ cur) {
  __shared__ int sm[256];
  const int t = threadIdx.x;
  const int g = blockIdx.x * 256 + t;
  const int v = cnt[g];
  sm[t] = v;
  __syncthreads();
  for (int s = 1; s < 256; s <<= 1) {
    const int a = (t >= s) ? sm[t - s] : 0;
    __syncthreads();
    sm[t] += a;
    __syncthreads();
  }
  const int ex = sm[t] - v + bsum[blockIdx.x];
  off[g] = ex;
  cur[g] = ex;
}

__global__ void reorder_kernel(const int* __restrict__ ei, const int* __restrict__ et,
                               int* __restrict__ cur, int* __restrict__ sorted_src) {
  const int e = blockIdx.x * 256 + threadIdx.x;
  const int seg = ei[N_EDGES + e] * NREL + et[e];
  const int pos = atomicAdd(&cur[seg], 1);
  sorted_src[pos] = ei[e];
}

// One wave per segment: gather x rows, f32-accumulate, write bf16 into Abf s-part.
__global__ void aggregate_kernel(const float* __restrict__ x,
                                 const int* __restrict__ cnt, const int* __restrict__ off,
                                 const int* __restrict__ sorted_src,
                                 unsigned short* __restrict__ abf) {
  const int seg = __builtin_amdgcn_readfirstlane(blockIdx.x * 4 + (threadIdx.x >> 6));
  const int lane = threadIdx.x & 63;
  const int ne = cnt[seg];
  const int o  = off[seg];
  const float4* x4 = (const float4*)x;
  float4 acc = make_float4(0.f, 0.f, 0.f, 0.f);
  float4 acc2 = make_float4(0.f, 0.f, 0.f, 0.f);
  int j = 0;
  for (; j + 1 < ne; j += 2) {
    const int s0 = sorted_src[o + j];
    const int s1 = sorted_src[o + j + 1];
    const float4 a = x4[(size_t)s0 * 64 + lane];
    const float4 b = x4[(size_t)s1 * 64 + lane];
    acc.x += a.x; acc.y += a.y; acc.z += a.z; acc.w += a.w;
    acc2.x += b.x; acc2.y += b.y; acc2.z += b.z; acc2.w += b.w;
  }
  if (j < ne) {
    const float4 a = x4[(size_t)sorted_src[o + j] * 64 + lane];
    acc.x += a.x; acc.y += a.y; acc.z += a.z; acc.w += a.w;
  }
  acc.x += acc2.x; acc.y += acc2.y; acc.z += acc2.z; acc.w += acc2.w;
  const int node = seg >> 3, r = seg & 7;
  union { unsigned short u[4]; uint2 q; } pk;
  pk.u[0] = f2bf(acc.x); pk.u[1] = f2bf(acc.y);
  pk.u[2] = f2bf(acc.z); pk.u[3] = f2bf(acc.w);
  *(uint2*)(abf + (size_t)node * KTOT + r * IN_DIM + lane * 4) = pk.q;
}

// Fill Abf[:, 2048:2304] = bf16(x)
__global__ void xcast_kernel(const float* __restrict__ x, unsigned short* __restrict__ abf) {
  const int id = blockIdx.x * 256 + threadIdx.x;   // 20000*64
  const int row = id >> 6, lane = id & 63;
  const float4 v = ((const float4*)x)[(size_t)row * 64 + lane];
  union { unsigned short u[4]; uint2 q; } pk;
  pk.u[0] = f2bf(v.x); pk.u[1] = f2bf(v.y);
  pk.u[2] = f2bf(v.z); pk.u[3] = f2bf(v.w);
  *(uint2*)(abf + (size_t)row * KTOT + KS + lane * 4) = pk.q;
}

// WcatT[n][k], n in [0,1024), k in [0,2304). n >= 800 zero-padded.
__global__ void build_wcat_kernel(const float* __restrict__ bases,
                                  const float* __restrict__ att,
                                  const float* __restrict__ root,
                                  unsigned short* __restrict__ wcatT) {
  const int k = blockIdx.x;
  const int n = blockIdx.y * 128 + threadIdx.x;
  float v = 0.f;
  if (n < OUT_DIM) {
    if (k < KS) {
      const int r = k >> 8, i = k & 255;
      #pragma unroll
      for (int b = 0; b < 8; ++b)
        v += att[r * 8 + b] * bases[((size_t)b * IN_DIM + i) * OUT_DIM + n];
    } else {
      v = root[(size_t)(k - KS) * OUT_DIM + n];
    }
  }
  wcatT[(size_t)n * KTOT + k] = f2bf(v);
}

// C[20000][800] = Abf[20000][2304] @ WcatT^T + bias.
// 128x256 tile, BK=64, 8 waves (2Mx4N, 64x64 each), double-buffered LDS via
// global_load_lds, counted vmcnt(6) (T4), both-sides XOR swizzle (T2),
// bijective XCD-chunk block swizzle (T1).
__global__ __launch_bounds__(512, 2) void gemm_kernel(
    const unsigned short* __restrict__ abf,
    const unsigned short* __restrict__ wcatT,
    const float* __restrict__ bias, float* __restrict__ out) {
  __shared__ __align__(16) char lds[2 * 49152];   // [buf][A 16K | B 32K]

  // T1: bijective XCD-chunk swizzle (m204). Row fastest within a chunk ->
  // same B panel (1.18 MB) stays L2-resident per XCD while A streams.
  const int lin = blockIdx.x;
  const int q8 = NWG >> 3, r8 = NWG & 7;          // 78, 4
  const int xcd = lin & 7, idx = lin >> 3;
  const int wg = (xcd < r8 ? xcd * (q8 + 1) : r8 * (q8 + 1) + (xcd - r8) * q8) + idx;
  const int row0 = (wg % MT) * BM;
  const int col0 = (wg / MT) * BN;

  const int tid = threadIdx.x;
  const int w = tid >> 6, l = tid & 63;
  const int wm = w >> 2, wn = w & 3;              // wave tile: rows wm*64, cols wn*64
  const int la = l & 15, lg = l >> 4;
  const int l3 = l >> 3;
  const int schunk = (l & 7) ^ l3;                // pre-swizzled global k-chunk (T2)

  // staging row bases: issue qq covers rows qq*64 + w*8 + l3
  int rA[2], rB[4];
  #pragma unroll
  for (int qq = 0; qq < 2; ++qq) {
    int ra = row0 + qq * 64 + w * 8 + l3;
    rA[qq] = (ra < N_NODES) ? ra : (N_NODES - 1);  // clamp: garbage rows never stored
  }
  #pragma unroll
  for (int qq = 0; qq < 4; ++qq) rB[qq] = col0 + qq * 64 + w * 8 + l3;

  f32x4_t acc[4][4];
  #pragma unroll
  for (int i = 0; i < 4; ++i)
    #pragma unroll
    for (int j = 0; j < 4; ++j)
      acc[i][j] = (f32x4_t)(0.0f);

  const bool wactive = (col0 + wn * 64) < OUT_DIM;  // last col tile: waves wn>=1 idle

  auto stage = [&](int buf, int kt) {
    char* lA = lds + buf * 49152 + w * 1024;
    char* lB = lds + buf * 49152 + 16384 + w * 1024;
    const size_t ko = (size_t)kt * BK + (size_t)schunk * 8;
    #pragma unroll
    for (int qq = 0; qq < 2; ++qq)
      gload16(abf + (size_t)rA[qq] * KTOT + ko, lA + qq * 8192);
    #pragma unroll
    for (int qq = 0; qq < 4; ++qq)
      gload16(wcatT + (size_t)rB[qq] * KTOT + ko, lB + qq * 8192);
  };

  int cur = 0;
  stage(0, 0);
  for (int kt = 0; kt < NKT; ++kt) {
    if (kt + 1 < NKT) {
      stage(cur ^ 1, kt + 1);                      // 6 loads stay in flight
      asm volatile("s_waitcnt vmcnt(6)" ::: "memory");   // T4: counted, not 0
    } else {
      asm volatile("s_waitcnt vmcnt(0)" ::: "memory");
    }
    __builtin_amdgcn_sched_barrier(0);
    __builtin_amdgcn_s_barrier();                  // buf[cur] staged for all waves
    __builtin_amdgcn_sched_barrier(0);

    if (wactive) {
      const char* Ab = lds + cur * 49152;
      const char* Bb = Ab + 16384;
      #pragma unroll
      for (int s = 0; s < 2; ++s) {
        short8_t af[4], bf[4];
        #pragma unroll
        for (int f = 0; f < 4; ++f) {
          const int rr = wm * 64 + f * 16 + la;
          af[f] = *(const short8_t*)(Ab + rr * 128 +
                    (((s * 4 + lg) << 4) ^ ((rr & 7) << 4)));
        }
        #pragma unroll
        for (int nf = 0; nf < 4; ++nf) {
          const int rr = wn * 64 + nf * 16 + la;
          bf[nf] = *(const short8_t*)(Bb + rr * 128 +
                    (((s * 4 + lg) << 4) ^ ((rr & 7) << 4)));
        }
        #pragma unroll
        for (int f = 0; f < 4; ++f)
          #pragma unroll
          for (int nf = 0; nf < 4; ++nf)
            acc[f][nf] = __builtin_amdgcn_mfma_f32_16x16x32_bf16(
                af[f], bf[nf], acc[f][nf], 0, 0, 0);
      }
    }
    asm volatile("s_waitcnt lgkmcnt(0)" ::: "memory");   // my ds_reads done
    __builtin_amdgcn_sched_barrier(0);
    __builtin_amdgcn_s_barrier();                  // safe to overwrite buf[cur] next iter
    __builtin_amdgcn_sched_barrier(0);
    cur ^= 1;
  }

  if (wactive) {
    #pragma unroll
    for (int nf = 0; nf < 4; ++nf) {
      const int gcol = col0 + wn * 64 + nf * 16 + la;
      if (gcol < OUT_DIM) {
        const float bv = bias[gcol];
        #pragma unroll
        for (int f = 0; f < 4; ++f) {
          const int gr0 = row0 + wm * 64 + f * 16 + lg * 4;
          #pragma unroll
          for (int j = 0; j < 4; ++j) {
            const int gr = gr0 + j;
            if (gr < N_NODES)
              out[(size_t)gr * OUT_DIM + gcol] = acc[f][nf][j] + bv;
          }
        }
      }
    }
  }
}

extern "C" void kernel_launch(void* const* d_in, const int* in_sizes, int n_in,
                              void* d_out, int out_size, void* d_ws, size_t ws_size,
                              hipStream_t stream) {
  const float* x     = (const float*)d_in[0];
  const int*   ei    = (const int*)d_in[1];
  const int*   et    = (const int*)d_in[2];
  const float* bases = (const float*)d_in[3];
  const float* att   = (const float*)d_in[4];
  const float* root  = (const float*)d_in[5];
  const float* bias  = (const float*)d_in[6];
  float* out = (float*)d_out;

  char* p = (char*)d_ws;
  unsigned short* abf   = (unsigned short*)p;  p += (size_t)N_NODES * KTOT * 2;  // 92,160,000
  unsigned short* wcatT = (unsigned short*)p;  p += (size_t)NPAD * KTOT * 2;     //  4,718,592
  int* cnt        = (int*)p;                   p += (size_t)NSEG * 4;
  int* off        = (int*)p;                   p += (size_t)NSEG * 4;
  int* cur        = (int*)p;                   p += (size_t)NSEG * 4;
  int* sorted_src = (int*)p;                   p += (size_t)N_EDGES * 4;
  int* bsum       = (int*)p;                   p += 4096;

  zero_counts_kernel<<<NB, 256, 0, stream>>>(cnt);
  hist_kernel<<<N_EDGES / 256, 256, 0, stream>>>(ei, et, cnt);
  scan_reduce_kernel<<<NB, 256, 0, stream>>>(cnt, bsum);
  scan_bsum_kernel<<<1, 1024, 0, stream>>>(bsum);
  scan_final_kernel<<<NB, 256, 0, stream>>>(cnt, bsum, off, cur);
  reorder_kernel<<<N_EDGES / 256, 256, 0, stream>>>(ei, et, cur, sorted_src);
  aggregate_kernel<<<NSEG / 4, 256, 0, stream>>>(x, cnt, off, sorted_src, abf);
  xcast_kernel<<<N_NODES * 64 / 256, 256, 0, stream>>>(x, abf);
  build_wcat_kernel<<<dim3(KTOT, 8), 128, 0, stream>>>(bases, att, root, wcatT);
  gemm_kernel<<<NWG, 512, 0, stream>>>(abf, wcatT, bias, out);
}